// Round 11
// baseline (964.568 us; speedup 1.0000x reference)
//
#include <hip/hip_runtime.h>

constexpr int D   = 128;
constexpr int G   = 64;
constexpr int OUT = 64;
constexpr int L   = 4;
#define BN_EPS 1e-5f

constexpr int BSH    = 9;            // bucket = dst >> 9  (512 nodes/bucket)
constexpr int BNODES = 1 << BSH;
constexpr int SC_CHUNK = 8192;       // edges per scatter block

typedef __attribute__((ext_vector_type(8))) short bf16x8;
typedef __attribute__((ext_vector_type(4))) short short4v;
typedef __attribute__((ext_vector_type(4))) float f32x4;
typedef unsigned short u16;

__device__ inline u16 f2bf(float f) {
    union { float f; unsigned u; } x; x.f = f;
    unsigned r = x.u + 0x7FFF + ((x.u >> 16) & 1);   // RNE
    return (u16)(r >> 16);
}
__device__ inline float bf2f(u16 u) {
    union { unsigned u; float f; } x; x.u = ((unsigned)u) << 16;
    return x.f;
}

// ================================================================ CSR build (bucket-sorted)
__global__ __launch_bounds__(256) void bucket_hist(const int* __restrict__ dst,
                                                   int* __restrict__ bktCnt,
                                                   int nE, int numB) {
    __shared__ int h[4096];
    const int tid = threadIdx.x;
    for (int i = tid; i < numB; i += 256) h[i] = 0;
    __syncthreads();
    const int stride = gridDim.x * 256;
    for (int e = blockIdx.x * 256 + tid; e < nE; e += stride)
        atomicAdd(&h[dst[e] >> BSH], 1);
    __syncthreads();
    for (int i = tid; i < numB; i += 256)
        if (h[i]) atomicAdd(&bktCnt[i], h[i]);
}

__global__ __launch_bounds__(256) void scan_buckets(const int* __restrict__ bktCnt,
                                                    int* __restrict__ bktOff,
                                                    int* __restrict__ bktCur,
                                                    int numB, int total) {
    __shared__ int sm[256];
    const int tid = threadIdx.x;
    int v[4];
    int s = 0;
#pragma unroll
    for (int j = 0; j < 4; ++j) {
        int i = tid * 4 + j;
        v[j] = (i < numB) ? bktCnt[i] : 0;
        s += v[j];
    }
    sm[tid] = s;
    __syncthreads();
    for (int off = 1; off < 256; off <<= 1) {
        int t = (tid >= off) ? sm[tid - off] : 0;
        __syncthreads();
        sm[tid] += t;
        __syncthreads();
    }
    int run = sm[tid] - s;
#pragma unroll
    for (int j = 0; j < 4; ++j) {
        int i = tid * 4 + j;
        if (i < numB) { bktOff[i] = run; bktCur[i] = run; }
        run += v[j];
    }
    if (tid == 0) bktOff[numB] = total;
}

__global__ __launch_bounds__(256) void bucket_scatter(const int* __restrict__ src,
                                                      const int* __restrict__ dst,
                                                      int* __restrict__ bktCur,
                                                      int2* __restrict__ sorted,
                                                      int nE, int numB) {
    __shared__ int h[1024];
    __shared__ int base[1024];
    const int tid = threadIdx.x;
    const int lo = blockIdx.x * SC_CHUNK;
    const int hi = min(lo + SC_CHUNK, nE);
    for (int i = tid; i < numB; i += 256) h[i] = 0;
    __syncthreads();
    for (int e = lo + tid; e < hi; e += 256)
        atomicAdd(&h[dst[e] >> BSH], 1);
    __syncthreads();
    for (int i = tid; i < numB; i += 256) {
        int c = h[i];
        base[i] = c ? atomicAdd(&bktCur[i], c) : 0;
        h[i] = 0;   // reuse as local cursor
    }
    __syncthreads();
    for (int e = lo + tid; e < hi; e += 256) {
        int d = dst[e];
        int b = d >> BSH;
        int pos = base[b] + atomicAdd(&h[b], 1);
        sorted[pos] = make_int2(src[e], d);
    }
}

__global__ __launch_bounds__(256) void bucket_deg(const int2* __restrict__ sorted,
                                                  const int* __restrict__ bktOff,
                                                  int* __restrict__ deg, int nN) {
    __shared__ int h[BNODES];
    const int tid = threadIdx.x;
    const int b = blockIdx.x;
    for (int j = tid; j < BNODES; j += 256) h[j] = 0;
    __syncthreads();
    const int lo = bktOff[b], hi = bktOff[b + 1];
    for (int i = lo + tid; i < hi; i += 256)
        atomicAdd(&h[sorted[i].y & (BNODES - 1)], 1);
    __syncthreads();
    const int node0 = b << BSH;
    for (int j = tid; j < BNODES; j += 256) {
        int n = node0 + j;
        if (n < nN) deg[n] = h[j];
    }
}

__global__ __launch_bounds__(256) void csr_fill2(const int2* __restrict__ sorted,
                                                 const int* __restrict__ bktOff,
                                                 const int* __restrict__ rowptr,
                                                 int* __restrict__ esrc, int nN) {
    __shared__ int cur[BNODES];
    const int tid = threadIdx.x;
    const int b = blockIdx.x;
    const int node0 = b << BSH;
    for (int j = tid; j < BNODES; j += 256) {
        int n = node0 + j;
        cur[j] = (n < nN) ? rowptr[n] : 0;
    }
    __syncthreads();
    const int lo = bktOff[b], hi = bktOff[b + 1];
    for (int i = lo + tid; i < hi; i += 256) {
        int2 e = sorted[i];
        int pos = atomicAdd(&cur[e.y & (BNODES - 1)], 1);
        esrc[pos] = e.x;
    }
}

// ================================================================ rowptr scan (over N)
constexpr int SCAN_B = 256;
constexpr int SCAN_E = 8;
constexpr int SCAN_CHUNK = SCAN_B * SCAN_E;

__global__ __launch_bounds__(SCAN_B) void scan_pass1(const int* __restrict__ deg,
                                                     int* __restrict__ rowptr,
                                                     int* __restrict__ bsum, int n) {
    __shared__ int sm[SCAN_B];
    const int tid = threadIdx.x;
    const int base = blockIdx.x * SCAN_CHUNK + tid * SCAN_E;
    int v[SCAN_E];
    int s = 0;
#pragma unroll
    for (int j = 0; j < SCAN_E; ++j) {
        v[j] = (base + j < n) ? deg[base + j] : 0;
        s += v[j];
    }
    sm[tid] = s;
    __syncthreads();
    for (int off = 1; off < SCAN_B; off <<= 1) {
        int t = (tid >= off) ? sm[tid - off] : 0;
        __syncthreads();
        sm[tid] += t;
        __syncthreads();
    }
    int run = sm[tid] - s;
#pragma unroll
    for (int j = 0; j < SCAN_E; ++j) {
        if (base + j < n) rowptr[base + j] = run;
        run += v[j];
    }
    if (tid == SCAN_B - 1) bsum[blockIdx.x] = sm[SCAN_B - 1];
}

__global__ void scan_pass2(int* __restrict__ bsum, int nb) {
    if (threadIdx.x == 0 && blockIdx.x == 0) {
        int t = 0;
        for (int i = 0; i < nb; ++i) {
            int s = bsum[i];
            bsum[i] = t;
            t += s;
        }
    }
}

__global__ __launch_bounds__(SCAN_B) void scan_pass3(int* __restrict__ rowptr,
                                                     const int* __restrict__ bsum,
                                                     int n, int total) {
    const int add = bsum[blockIdx.x];
    const int base = blockIdx.x * SCAN_CHUNK + threadIdx.x * SCAN_E;
#pragma unroll
    for (int j = 0; j < SCAN_E; ++j)
        if (base + j < n) rowptr[base + j] += add;
    if (blockIdx.x == 0 && threadIdx.x == 0) rowptr[n] = total;
}

// ================================================================ weights -> bf16 transposed: Wt[mat][col][k]
__global__ void prep_weights(const float* __restrict__ W1, const float* __restrict__ W2,
                             u16* __restrict__ Wt) {
    const int m = blockIdx.x;  // 0..2L-1
    const float* W = (m < L) ? (W1 + (size_t)m * D * D) : (W2 + (size_t)(m - L) * D * D);
    u16* o = Wt + (size_t)m * D * D;
    for (int e = threadIdx.x * 4; e < D * D; e += 256 * 4) {
        float4 v = *reinterpret_cast<const float4*>(W + e);
        int k = e >> 7, c = e & 127;
        o[(c + 0) * D + k] = f2bf(v.x);
        o[(c + 1) * D + k] = f2bf(v.y);
        o[(c + 2) * D + k] = f2bf(v.z);
        o[(c + 3) * D + k] = f2bf(v.w);
    }
}

// ================================================================ h0 -> bf16 + pool0
__global__ __launch_bounds__(256) void convert_pool(const float* __restrict__ h, const int* __restrict__ gid,
                                                    u16* __restrict__ hbf, float* __restrict__ pooled,
                                                    int nRows) {
    const int tid = threadIdx.x;
    const int c = tid & 127;
    const int rsub = tid >> 7;
    const long long row0 = (long long)blockIdx.x * 64;
    float acc = 0.f;
    int cur = -1;
    for (int r = rsub; r < 64; r += 2) {
        long long row = row0 + r;
        if (row >= nRows) break;
        float v = h[row * D + c];
        hbf[row * D + c] = f2bf(v);
        int g = gid[row];
        if (g != cur) {
            if (cur >= 0) atomicAdd(&pooled[(long long)cur * D + c], acc);
            cur = g;
            acc = 0.f;
        }
        acc += v;
    }
    if (cur >= 0) atomicAdd(&pooled[(long long)cur * D + c], acc);
}

// ================================================================ aggregation: 16-lane groups, bf16x8 (16B) loads, 12-deep MLP
// (12 chosen so VGPR <= 64 -> still 8 waves/SIMD; +50% in-flight vs 8-deep)
__global__ __launch_bounds__(256) void agg_gather(const u16* __restrict__ hbf,
                                                  const int* __restrict__ rowptr,
                                                  const int* __restrict__ esrc,
                                                  const float* __restrict__ epsP,
                                                  u16* __restrict__ xbf, int nRows) {
    const int r = blockIdx.x * 16 + (threadIdx.x >> 4);
    if (r >= nRows) return;
    const int c = (threadIdx.x & 15) * 8;
    const int beg = rowptr[r], end = rowptr[r + 1];
    const float ep = 1.0f + epsP[0];
    bf16x8 a = *reinterpret_cast<const bf16x8*>(hbf + (size_t)r * D + c);
    float acc[8];
#pragma unroll
    for (int j = 0; j < 8; ++j) acc[j] = ep * bf2f((u16)a[j]);

    int e = beg;
    for (; e + 12 <= end; e += 12) {
        bf16x8 v[12];
#pragma unroll
        for (int q = 0; q < 12; ++q) {
            int s = esrc[e + q];
            v[q] = *reinterpret_cast<const bf16x8*>(hbf + (size_t)s * D + c);
        }
#pragma unroll
        for (int j = 0; j < 8; ++j) {
            float t0 = (bf2f((u16)v[0][j]) + bf2f((u16)v[1][j])) + (bf2f((u16)v[2][j]) + bf2f((u16)v[3][j]));
            float t1 = (bf2f((u16)v[4][j]) + bf2f((u16)v[5][j])) + (bf2f((u16)v[6][j]) + bf2f((u16)v[7][j]));
            float t2 = (bf2f((u16)v[8][j]) + bf2f((u16)v[9][j])) + (bf2f((u16)v[10][j]) + bf2f((u16)v[11][j]));
            acc[j] += (t0 + t1) + t2;
        }
    }
    for (; e + 4 <= end; e += 4) {
        bf16x8 v[4];
#pragma unroll
        for (int q = 0; q < 4; ++q) {
            int s = esrc[e + q];
            v[q] = *reinterpret_cast<const bf16x8*>(hbf + (size_t)s * D + c);
        }
#pragma unroll
        for (int j = 0; j < 8; ++j)
            acc[j] += (bf2f((u16)v[0][j]) + bf2f((u16)v[1][j])) + (bf2f((u16)v[2][j]) + bf2f((u16)v[3][j]));
    }
    for (; e < end; ++e) {
        int s = esrc[e];
        bf16x8 v = *reinterpret_cast<const bf16x8*>(hbf + (size_t)s * D + c);
#pragma unroll
        for (int j = 0; j < 8; ++j) acc[j] += bf2f((u16)v[j]);
    }
    bf16x8 o;
#pragma unroll
    for (int j = 0; j < 8; ++j) o[j] = (short)f2bf(acc[j]);
    *reinterpret_cast<bf16x8*>(xbf + (size_t)r * D + c) = o;
}

// ================================================================ MFMA GEMM v2: A direct global->reg (no LDS), W-only LDS (32KB),
// shuffle-reduced BN-stat epilogue. MODE 1: A=relu(bn(in)); MODE 2: A=in.
// In-place safe: each WAVE reads only the 32 rows it writes.
template <int MODE>
__global__ __launch_bounds__(256) void gemm_mfma(
    const u16* __restrict__ A, const u16* __restrict__ Wt, const float* __restrict__ bias,
    const float* __restrict__ pSum, const float* __restrict__ pSq,
    const float* __restrict__ bng, const float* __restrict__ bnb, float invN,
    u16* __restrict__ outP, float* __restrict__ gsum, float* __restrict__ gsq,
    int nRows) {
    __shared__ u16 wL[D * D];   // 32 KB swizzled [col][k]
    __shared__ float redS[D], redQ[D];
    __shared__ float scL[D], shL[D];

    const int tid = threadIdx.x;
    const int row0 = blockIdx.x * 128;
    const int lane = tid & 63;
    const int wv = tid >> 6;
    const int wrow = wv * 32;
    const int lr = lane & 15;
    const int lb = lane >> 4;

    // --- issue A-fragment loads early (raw bf16, latency hidden by W staging)
    bf16x8 aR[2][4];
    bool valid[2];
#pragma unroll
    for (int m = 0; m < 2; ++m) {
        int row = row0 + wrow + m * 16 + lr;
        valid[m] = row < nRows;
        const u16* p = A + (size_t)(valid[m] ? row : (nRows - 1)) * D + lb * 8;
#pragma unroll
        for (int kk = 0; kk < 4; ++kk)
            aR[m][kk] = *reinterpret_cast<const bf16x8*>(p + kk * 32);
    }

    // --- stage W (32 KB, swizzled)
    for (int o = tid * 8; o < D * D; o += 2048) {
        bf16x8 v = *reinterpret_cast<const bf16x8*>(Wt + o);
        int byte = o * 2, r = byte >> 8;
        *reinterpret_cast<bf16x8*>((char*)wL + (byte ^ ((r & 7) << 4))) = v;
    }
    if (tid < D) {
        redS[tid] = 0.f; redQ[tid] = 0.f;
        if (MODE == 1) {
            float m = pSum[tid] * invN;
            float v = pSq[tid] * invN - m * m;
            float sc = bng[tid] * rsqrtf(v + BN_EPS);
            scL[tid] = sc;
            shL[tid] = bnb[tid] - m * sc;
        }
    }
    __syncthreads();

    // --- MODE1: BN+ReLU transform in registers
    if (MODE == 1) {
#pragma unroll
        for (int m = 0; m < 2; ++m)
#pragma unroll
            for (int kk = 0; kk < 4; ++kk)
#pragma unroll
                for (int j = 0; j < 8; ++j) {
                    int c = kk * 32 + lb * 8 + j;
                    float t = fmaxf(bf2f((u16)aR[m][kk][j]) * scL[c] + shL[c], 0.f);
                    aR[m][kk][j] = (short)f2bf(t);
                }
    }
#pragma unroll
    for (int m = 0; m < 2; ++m)
        if (!valid[m])
#pragma unroll
            for (int kk = 0; kk < 4; ++kk) aR[m][kk] = bf16x8{};

    // --- MFMA: 64 x 16x16x32
    f32x4 acc[2][8] = {};
#pragma unroll
    for (int kk = 0; kk < 4; ++kk) {
#pragma unroll
        for (int n = 0; n < 8; ++n) {
            int cr = n * 16 + lr;
            int byte = cr * 256 + kk * 64 + lb * 16;
            bf16x8 bF = *reinterpret_cast<const bf16x8*>((char*)wL + (byte ^ ((cr & 7) << 4)));
            acc[0][n] = __builtin_amdgcn_mfma_f32_16x16x32_bf16(aR[0][kk], bF, acc[0][n], 0, 0, 0);
            acc[1][n] = __builtin_amdgcn_mfma_f32_16x16x32_bf16(aR[1][kk], bF, acc[1][n], 0, 0, 0);
        }
    }

    // --- epilogue: bias, store bf16, BN stats (shuffle-reduce over lb, then LDS, then global)
    float ls[8], lq[8];
#pragma unroll
    for (int n = 0; n < 8; ++n) { ls[n] = 0.f; lq[n] = 0.f; }
#pragma unroll
    for (int n = 0; n < 8; ++n) {
        int col = n * 16 + lr;
        float bv = bias[col];
#pragma unroll
        for (int m = 0; m < 2; ++m) {
#pragma unroll
            for (int j = 0; j < 4; ++j) {
                int row = row0 + wrow + m * 16 + lb * 4 + j;
                if (row < nRows) {
                    float o = acc[m][n][j] + bv;
                    outP[(size_t)row * D + col] = f2bf(o);
                    ls[n] += o; lq[n] += o * o;
                }
            }
        }
    }
#pragma unroll
    for (int n = 0; n < 8; ++n) {
        float s = ls[n], q = lq[n];
        s += __shfl_xor(s, 16); q += __shfl_xor(q, 16);
        s += __shfl_xor(s, 32); q += __shfl_xor(q, 32);
        if (lb == 0) {
            atomicAdd(&redS[n * 16 + lr], s);
            atomicAdd(&redQ[n * 16 + lr], q);
        }
    }
    __syncthreads();
    if (tid < D) {
        atomicAdd(&gsum[tid], redS[tid]);
        atomicAdd(&gsq[tid], redQ[tid]);
    }
}

// ================================================================ stats of relu(bn2(z)), z in bf16
__global__ __launch_bounds__(256) void relu_bn_stats(const u16* __restrict__ z,
                                                     const float* __restrict__ pSum, const float* __restrict__ pSq,
                                                     const float* __restrict__ bng, const float* __restrict__ bnb,
                                                     float invN,
                                                     float* __restrict__ gsum, float* __restrict__ gsq,
                                                     long long n8) {
    __shared__ float redS[D], redQ[D];
    const int tid = threadIdx.x;
    if (tid < D) { redS[tid] = 0.f; redQ[tid] = 0.f; }
    __syncthreads();
    const int c = (tid & 15) * 8;
    float sc[8], sh[8];
#pragma unroll
    for (int j = 0; j < 8; ++j) {
        float m = pSum[c + j] * invN;
        float v = pSq[c + j] * invN - m * m;
        float s = bng[c + j] * rsqrtf(v + BN_EPS);
        sc[j] = s;
        sh[j] = bnb[c + j] - m * s;
    }
    const long long stride = (long long)gridDim.x * blockDim.x;
    float ls[8] = {}, lq[8] = {};
    for (long long i = (long long)blockIdx.x * blockDim.x + tid; i < n8; i += stride) {
        bf16x8 v = *reinterpret_cast<const bf16x8*>(z + i * 8);
#pragma unroll
        for (int j = 0; j < 8; ++j) {
            float t = fmaxf(bf2f((u16)v[j]) * sc[j] + sh[j], 0.f);
            ls[j] += t; lq[j] += t * t;
        }
    }
#pragma unroll
    for (int j = 0; j < 8; ++j) {
        atomicAdd(&redS[c + j], ls[j]);
        atomicAdd(&redQ[c + j], lq[j]);
    }
    __syncthreads();
    if (tid < D) {
        atomicAdd(&gsum[tid], redS[tid]);
        atomicAdd(&gsq[tid], redQ[tid]);
    }
}

// ================================================================ h = relu(bn3(relu(bn2(z)))) -> hbf (bf16) + pooling (fp32)
__global__ __launch_bounds__(256) void final_apply_pool(
    const u16* __restrict__ z, const int* __restrict__ gid,
    const float* __restrict__ p1S, const float* __restrict__ p1Q,
    const float* __restrict__ g2, const float* __restrict__ b2v,
    const float* __restrict__ p2S, const float* __restrict__ p2Q,
    const float* __restrict__ g3, const float* __restrict__ b3v,
    float invN, u16* __restrict__ hbf, float* __restrict__ pooled, int nRows) {
    const int tid = threadIdx.x;
    const int c = tid & 127;
    const int rsub = tid >> 7;
    const long long row0 = (long long)blockIdx.x * 64;

    float m = p1S[c] * invN;
    float va = p1Q[c] * invN - m * m;
    float a2 = g2[c] * rsqrtf(va + BN_EPS);
    float f2v = b2v[c] - m * a2;
    m = p2S[c] * invN;
    va = p2Q[c] * invN - m * m;
    float a3 = g3[c] * rsqrtf(va + BN_EPS);
    float f3v = b3v[c] - m * a3;

    float acc = 0.f;
    int cur = -1;
    for (int r = rsub; r < 64; r += 2) {
        long long row = row0 + r;
        if (row >= nRows) break;
        float v = bf2f(z[row * D + c]);
        v = fmaxf(fmaxf(v * a2 + f2v, 0.f) * a3 + f3v, 0.f);
        hbf[row * D + c] = f2bf(v);
        int g = gid[row];
        if (g != cur) {
            if (cur >= 0) atomicAdd(&pooled[(long long)cur * D + c], acc);
            cur = g;
            acc = 0.f;
        }
        acc += v;
    }
    if (cur >= 0) atomicAdd(&pooled[(long long)cur * D + c], acc);
}

// ================================================================ prediction heads: one block per graph
__global__ __launch_bounds__(256) void pred_heads(const float* __restrict__ pooled0,
                                                  const float* __restrict__ pooledL,
                                                  const float* __restrict__ pW,
                                                  const float* __restrict__ pb,
                                                  float* __restrict__ score) {
    __shared__ float red[256];
    __shared__ float pL[D];
    const int g = blockIdx.x;
    const int o = threadIdx.x & 63;
    const int ks = threadIdx.x >> 6;           // 0..3, each covers 32 k's
    float acc = 0.f;
    for (int i = 0; i <= L; ++i) {
        const float* p = (i == 0) ? (pooled0 + (size_t)g * D)
                                  : (pooledL + (size_t)(i - 1) * G * D + (size_t)g * D);
        if (threadIdx.x < D) pL[threadIdx.x] = p[threadIdx.x];
        __syncthreads();
        const float* w = pW + (size_t)i * D * OUT + (size_t)ks * 32 * OUT + o;
        float s = 0.f;
#pragma unroll
        for (int kk = 0; kk < 32; ++kk)
            s += pL[ks * 32 + kk] * w[kk * OUT];
        acc += s;
        if (ks == 0) acc += pb[i * OUT + o];
        __syncthreads();
    }
    red[threadIdx.x] = acc;
    __syncthreads();
    if (ks == 0)
        score[(size_t)g * OUT + o] = red[o] + red[64 + o] + red[128 + o] + red[192 + o];
}

// ================================================================
extern "C" void kernel_launch(void* const* d_in, const int* in_sizes, int n_in,
                              void* d_out, int out_size, void* d_ws, size_t ws_size,
                              hipStream_t stream) {
    const float* h0  = (const float*)d_in[0];
    const int*   src = (const int*)d_in[2];
    const int*   dst = (const int*)d_in[3];
    const int*   gid = (const int*)d_in[4];
    const float* eps = (const float*)d_in[5];
    const float* W1  = (const float*)d_in[6];
    const float* b1  = (const float*)d_in[7];
    const float* W2  = (const float*)d_in[8];
    const float* b2  = (const float*)d_in[9];
    const float* bn1g = (const float*)d_in[10];
    const float* bn1b = (const float*)d_in[11];
    const float* bn2g = (const float*)d_in[12];
    const float* bn2b = (const float*)d_in[13];
    const float* bn3g = (const float*)d_in[14];
    const float* bn3b = (const float*)d_in[15];
    const float* pW  = (const float*)d_in[16];
    const float* pb  = (const float*)d_in[17];

    const int N = in_sizes[0] / D;
    const int E = in_sizes[2];
    const size_t nd = (size_t)N * D;
    const int numB = (N + BNODES - 1) >> BSH;

    // ---- workspace layout
    u16*   hbf  = (u16*)d_ws;                // N*D bf16
    u16*   xbf  = hbf + nd;                  // N*D bf16 (x -> y -> z in place)
    u16*   Wt   = xbf + nd;                  // 2L*D*D bf16
    float* stats = (float*)(Wt + (size_t)2 * L * D * D);  // L*3 pairs of [128+128]
    float* pooled0 = stats + (size_t)L * 3 * 2 * D;       // G*D
    int*   bktCnt = (int*)(pooled0 + (size_t)G * D);      // 4096 (zeroed with stats)
    int*   bktOff = bktCnt + 4096;           // numB+1
    int*   bktCur = bktOff + 4096;           // numB
    int*   deg    = bktCur + 4096;           // N
    int*   rowptr = deg + N;                 // N+1
    int*   esrc   = rowptr + (N + 1);        // E
    int*   bsum   = esrc + E;                // scan block sums (~N/2048)
    int2*  sorted = (int2*)(((size_t)(bsum + 4096) + 15) & ~(size_t)15);  // E int2

    float* score = (float*)d_out;
    float* pooledOut = score + G * OUT;      // pooled[1..4]

    auto S = [&](int i, int j) { return stats + (size_t)(i * 3 + j) * 2 * D; };
    auto Q = [&](int i, int j) { return stats + (size_t)(i * 3 + j) * 2 * D + D; };

    const int nb = (N + SCAN_CHUNK - 1) / SCAN_CHUNK;
    const int sgrid = (E + SC_CHUNK - 1) / SC_CHUNK;
    const int hgrid = (E + 2047) / 2048;
    const int poolGrid = (N + 63) / 64;
    const int ggrid = (N + 127) / 128;
    const int agrid = (N + 15) / 16;
    const long long n8 = (long long)N * (D / 8);
    const float invN = 1.0f / (float)N;

    // one memset covers stats + pooled0 + bktCnt (contiguous)
    const size_t zeroBytes = ((size_t)L * 3 * 2 * D + (size_t)G * D) * sizeof(float) + 4096 * sizeof(int);
    hipMemsetAsync(stats, 0, zeroBytes, stream);
    hipMemsetAsync(d_out, 0, (size_t)out_size * sizeof(float), stream);

    // ---- CSR build (bucket-sorted) + weight prep
    bucket_hist<<<hgrid, 256, 0, stream>>>(dst, bktCnt, E, numB);
    prep_weights<<<2 * L, 256, 0, stream>>>(W1, W2, Wt);
    scan_buckets<<<1, 256, 0, stream>>>(bktCnt, bktOff, bktCur, numB, E);
    bucket_scatter<<<sgrid, 256, 0, stream>>>(src, dst, bktCur, sorted, E, numB);
    bucket_deg<<<numB, 256, 0, stream>>>(sorted, bktOff, deg, N);
    scan_pass1<<<nb, SCAN_B, 0, stream>>>(deg, rowptr, bsum, N);
    scan_pass2<<<1, 64, 0, stream>>>(bsum, nb);
    scan_pass3<<<nb, SCAN_B, 0, stream>>>(rowptr, bsum, N, E);
    csr_fill2<<<numB, 256, 0, stream>>>(sorted, bktOff, rowptr, esrc, N);

    // ---- h0 -> bf16 + pool0
    convert_pool<<<poolGrid, 256, 0, stream>>>(h0, gid, hbf, pooled0, N);

    for (int i = 0; i < L; ++i) {
        agg_gather<<<agrid, 256, 0, stream>>>(hbf, rowptr, esrc, eps + i, xbf, N);

        // y = x @ W1 + b1 (bf16, in place on xbf) + stats P0
        gemm_mfma<2><<<ggrid, 256, 0, stream>>>(
            xbf, Wt + (size_t)i * D * D, b1 + (size_t)i * D,
            nullptr, nullptr, nullptr, nullptr, invN,
            xbf, S(i, 0), Q(i, 0), N);

        // z = relu(bn1(y)) @ W2 + b2 (bf16, in place on xbf) + stats P1
        gemm_mfma<1><<<ggrid, 256, 0, stream>>>(
            xbf, Wt + (size_t)(L + i) * D * D, b2 + (size_t)i * D,
            S(i, 0), Q(i, 0), bn1g + (size_t)i * D, bn1b + (size_t)i * D, invN,
            xbf, S(i, 1), Q(i, 1), N);

        // stats P2 of relu(bn2(z))
        relu_bn_stats<<<1024, 256, 0, stream>>>(
            xbf, S(i, 1), Q(i, 1), bn2g + (size_t)i * D, bn2b + (size_t)i * D, invN,
            S(i, 2), Q(i, 2), n8);

        // h = relu(bn3(relu(bn2(z)))) -> hbf + pooled
        final_apply_pool<<<poolGrid, 256, 0, stream>>>(
            xbf, gid,
            S(i, 1), Q(i, 1), bn2g + (size_t)i * D, bn2b + (size_t)i * D,
            S(i, 2), Q(i, 2), bn3g + (size_t)i * D, bn3b + (size_t)i * D,
            invN, hbf, pooledOut + (size_t)i * G * D, N);
    }

    pred_heads<<<G, 256, 0, stream>>>(pooled0, pooledOut, pW, pb, score);
}

// Round 12
// 875.273 us; speedup vs baseline: 1.1020x; 1.1020x over previous
//
#include <hip/hip_runtime.h>

constexpr int D   = 128;
constexpr int G   = 64;
constexpr int OUT = 64;
constexpr int L   = 4;
#define BN_EPS 1e-5f

constexpr int BSH    = 9;            // bucket = dst >> 9  (512 nodes/bucket)
constexpr int BNODES = 1 << BSH;
constexpr int SC_CHUNK = 8192;       // edges per scatter block
// packed edge: src in bits 0..16 (N < 2^17), dst&511 in bits 17..25
constexpr int SRC_BITS = 17;
constexpr int SRC_MASK = (1 << SRC_BITS) - 1;

typedef __attribute__((ext_vector_type(8))) short bf16x8;
typedef __attribute__((ext_vector_type(4))) short short4v;
typedef __attribute__((ext_vector_type(4))) float f32x4;
typedef unsigned short u16;

__device__ inline u16 f2bf(float f) {
    union { float f; unsigned u; } x; x.f = f;
    unsigned r = x.u + 0x7FFF + ((x.u >> 16) & 1);   // RNE
    return (u16)(r >> 16);
}
__device__ inline float bf2f(u16 u) {
    union { unsigned u; float f; } x; x.u = ((unsigned)u) << 16;
    return x.f;
}

// ================================================================ CSR build (bucket-sorted)
__global__ __launch_bounds__(256) void bucket_hist(const int* __restrict__ dst,
                                                   int* __restrict__ bktCnt,
                                                   int nE, int numB) {
    __shared__ int h[4096];
    const int tid = threadIdx.x;
    for (int i = tid; i < numB; i += 256) h[i] = 0;
    __syncthreads();
    const int stride = gridDim.x * 256;
    for (int e = blockIdx.x * 256 + tid; e < nE; e += stride)
        atomicAdd(&h[dst[e] >> BSH], 1);
    __syncthreads();
    for (int i = tid; i < numB; i += 256)
        if (h[i]) atomicAdd(&bktCnt[i], h[i]);
}

__global__ __launch_bounds__(256) void scan_buckets(const int* __restrict__ bktCnt,
                                                    int* __restrict__ bktOff,
                                                    int* __restrict__ bktCur,
                                                    int numB, int total) {
    __shared__ int sm[256];
    const int tid = threadIdx.x;
    int v[4];
    int s = 0;
#pragma unroll
    for (int j = 0; j < 4; ++j) {
        int i = tid * 4 + j;
        v[j] = (i < numB) ? bktCnt[i] : 0;
        s += v[j];
    }
    sm[tid] = s;
    __syncthreads();
    for (int off = 1; off < 256; off <<= 1) {
        int t = (tid >= off) ? sm[tid - off] : 0;
        __syncthreads();
        sm[tid] += t;
        __syncthreads();
    }
    int run = sm[tid] - s;
#pragma unroll
    for (int j = 0; j < 4; ++j) {
        int i = tid * 4 + j;
        if (i < numB) { bktOff[i] = run; bktCur[i] = run; }
        run += v[j];
    }
    if (tid == 0) bktOff[numB] = total;
}

// block-aggregated scatter; writes PACKED edges (4B instead of 8B)
__global__ __launch_bounds__(256) void bucket_scatter(const int* __restrict__ src,
                                                      const int* __restrict__ dst,
                                                      int* __restrict__ bktCur,
                                                      int* __restrict__ sorted,
                                                      int nE, int numB) {
    __shared__ int h[1024];
    __shared__ int base[1024];
    const int tid = threadIdx.x;
    const int lo = blockIdx.x * SC_CHUNK;
    const int hi = min(lo + SC_CHUNK, nE);
    for (int i = tid; i < numB; i += 256) h[i] = 0;
    __syncthreads();
    for (int e = lo + tid; e < hi; e += 256)
        atomicAdd(&h[dst[e] >> BSH], 1);
    __syncthreads();
    for (int i = tid; i < numB; i += 256) {
        int c = h[i];
        base[i] = c ? atomicAdd(&bktCur[i], c) : 0;
        h[i] = 0;   // reuse as local cursor
    }
    __syncthreads();
    for (int e = lo + tid; e < hi; e += 256) {
        int d = dst[e];
        int b = d >> BSH;
        int pos = base[b] + atomicAdd(&h[b], 1);
        sorted[pos] = src[e] | ((d & (BNODES - 1)) << SRC_BITS);
    }
}

__global__ __launch_bounds__(256) void bucket_deg(const int* __restrict__ sorted,
                                                  const int* __restrict__ bktOff,
                                                  int* __restrict__ deg, int nN) {
    __shared__ int h[BNODES];
    const int tid = threadIdx.x;
    const int b = blockIdx.x;
    for (int j = tid; j < BNODES; j += 256) h[j] = 0;
    __syncthreads();
    const int lo = bktOff[b], hi = bktOff[b + 1];
    for (int i = lo + tid; i < hi; i += 256)
        atomicAdd(&h[(sorted[i] >> SRC_BITS) & (BNODES - 1)], 1);
    __syncthreads();
    const int node0 = b << BSH;
    for (int j = tid; j < BNODES; j += 256) {
        int n = node0 + j;
        if (n < nN) deg[n] = h[j];
    }
}

__global__ __launch_bounds__(256) void csr_fill2(const int* __restrict__ sorted,
                                                 const int* __restrict__ bktOff,
                                                 const int* __restrict__ rowptr,
                                                 int* __restrict__ esrc, int nN) {
    __shared__ int cur[BNODES];
    const int tid = threadIdx.x;
    const int b = blockIdx.x;
    const int node0 = b << BSH;
    for (int j = tid; j < BNODES; j += 256) {
        int n = node0 + j;
        cur[j] = (n < nN) ? rowptr[n] : 0;
    }
    __syncthreads();
    const int lo = bktOff[b], hi = bktOff[b + 1];
    for (int i = lo + tid; i < hi; i += 256) {
        int p = sorted[i];
        int pos = atomicAdd(&cur[(p >> SRC_BITS) & (BNODES - 1)], 1);
        esrc[pos] = p & SRC_MASK;
    }
}

// ================================================================ rowptr scan (over N)
constexpr int SCAN_B = 256;
constexpr int SCAN_E = 8;
constexpr int SCAN_CHUNK = SCAN_B * SCAN_E;

__global__ __launch_bounds__(SCAN_B) void scan_pass1(const int* __restrict__ deg,
                                                     int* __restrict__ rowptr,
                                                     int* __restrict__ bsum, int n) {
    __shared__ int sm[SCAN_B];
    const int tid = threadIdx.x;
    const int base = blockIdx.x * SCAN_CHUNK + tid * SCAN_E;
    int v[SCAN_E];
    int s = 0;
#pragma unroll
    for (int j = 0; j < SCAN_E; ++j) {
        v[j] = (base + j < n) ? deg[base + j] : 0;
        s += v[j];
    }
    sm[tid] = s;
    __syncthreads();
    for (int off = 1; off < SCAN_B; off <<= 1) {
        int t = (tid >= off) ? sm[tid - off] : 0;
        __syncthreads();
        sm[tid] += t;
        __syncthreads();
    }
    int run = sm[tid] - s;
#pragma unroll
    for (int j = 0; j < SCAN_E; ++j) {
        if (base + j < n) rowptr[base + j] = run;
        run += v[j];
    }
    if (tid == SCAN_B - 1) bsum[blockIdx.x] = sm[SCAN_B - 1];
}

__global__ void scan_pass2(int* __restrict__ bsum, int nb) {
    if (threadIdx.x == 0 && blockIdx.x == 0) {
        int t = 0;
        for (int i = 0; i < nb; ++i) {
            int s = bsum[i];
            bsum[i] = t;
            t += s;
        }
    }
}

__global__ __launch_bounds__(SCAN_B) void scan_pass3(int* __restrict__ rowptr,
                                                     const int* __restrict__ bsum,
                                                     int n, int total) {
    const int add = bsum[blockIdx.x];
    const int base = blockIdx.x * SCAN_CHUNK + threadIdx.x * SCAN_E;
#pragma unroll
    for (int j = 0; j < SCAN_E; ++j)
        if (base + j < n) rowptr[base + j] += add;
    if (blockIdx.x == 0 && threadIdx.x == 0) rowptr[n] = total;
}

// ================================================================ weights -> bf16 transposed: Wt[mat][col][k]
__global__ void prep_weights(const float* __restrict__ W1, const float* __restrict__ W2,
                             u16* __restrict__ Wt) {
    const int m = blockIdx.x;  // 0..2L-1
    const float* W = (m < L) ? (W1 + (size_t)m * D * D) : (W2 + (size_t)(m - L) * D * D);
    u16* o = Wt + (size_t)m * D * D;
    for (int e = threadIdx.x * 4; e < D * D; e += 256 * 4) {
        float4 v = *reinterpret_cast<const float4*>(W + e);
        int k = e >> 7, c = e & 127;
        o[(c + 0) * D + k] = f2bf(v.x);
        o[(c + 1) * D + k] = f2bf(v.y);
        o[(c + 2) * D + k] = f2bf(v.z);
        o[(c + 3) * D + k] = f2bf(v.w);
    }
}

// ================================================================ h0 -> bf16 + pool0
__global__ __launch_bounds__(256) void convert_pool(const float* __restrict__ h, const int* __restrict__ gid,
                                                    u16* __restrict__ hbf, float* __restrict__ pooled,
                                                    int nRows) {
    const int tid = threadIdx.x;
    const int c = tid & 127;
    const int rsub = tid >> 7;
    const long long row0 = (long long)blockIdx.x * 64;
    float acc = 0.f;
    int cur = -1;
    for (int r = rsub; r < 64; r += 2) {
        long long row = row0 + r;
        if (row >= nRows) break;
        float v = h[row * D + c];
        hbf[row * D + c] = f2bf(v);
        int g = gid[row];
        if (g != cur) {
            if (cur >= 0) atomicAdd(&pooled[(long long)cur * D + c], acc);
            cur = g;
            acc = 0.f;
        }
        acc += v;
    }
    if (cur >= 0) atomicAdd(&pooled[(long long)cur * D + c], acc);
}

// ================================================================ aggregation: 16-lane groups, bf16x8 (16B) loads, 8-deep MLP
// (R10-proven config: VGPR 44, occ 44%, ~60 µs — at L2-miss-service roofline)
__global__ __launch_bounds__(256) void agg_gather(const u16* __restrict__ hbf,
                                                  const int* __restrict__ rowptr,
                                                  const int* __restrict__ esrc,
                                                  const float* __restrict__ epsP,
                                                  u16* __restrict__ xbf, int nRows) {
    const int r = blockIdx.x * 16 + (threadIdx.x >> 4);
    if (r >= nRows) return;
    const int c = (threadIdx.x & 15) * 8;
    const int beg = rowptr[r], end = rowptr[r + 1];
    const float ep = 1.0f + epsP[0];
    bf16x8 a = *reinterpret_cast<const bf16x8*>(hbf + (size_t)r * D + c);
    float acc[8];
#pragma unroll
    for (int j = 0; j < 8; ++j) acc[j] = ep * bf2f((u16)a[j]);

    int e = beg;
    for (; e + 8 <= end; e += 8) {
        bf16x8 v[8];
#pragma unroll
        for (int q = 0; q < 8; ++q) {
            int s = esrc[e + q];
            v[q] = *reinterpret_cast<const bf16x8*>(hbf + (size_t)s * D + c);
        }
#pragma unroll
        for (int j = 0; j < 8; ++j) {
            float t0 = (bf2f((u16)v[0][j]) + bf2f((u16)v[1][j])) + (bf2f((u16)v[2][j]) + bf2f((u16)v[3][j]));
            float t1 = (bf2f((u16)v[4][j]) + bf2f((u16)v[5][j])) + (bf2f((u16)v[6][j]) + bf2f((u16)v[7][j]));
            acc[j] += t0 + t1;
        }
    }
    for (; e + 4 <= end; e += 4) {
        bf16x8 v[4];
#pragma unroll
        for (int q = 0; q < 4; ++q) {
            int s = esrc[e + q];
            v[q] = *reinterpret_cast<const bf16x8*>(hbf + (size_t)s * D + c);
        }
#pragma unroll
        for (int j = 0; j < 8; ++j)
            acc[j] += (bf2f((u16)v[0][j]) + bf2f((u16)v[1][j])) + (bf2f((u16)v[2][j]) + bf2f((u16)v[3][j]));
    }
    for (; e < end; ++e) {
        int s = esrc[e];
        bf16x8 v = *reinterpret_cast<const bf16x8*>(hbf + (size_t)s * D + c);
#pragma unroll
        for (int j = 0; j < 8; ++j) acc[j] += bf2f((u16)v[j]);
    }
    bf16x8 o;
#pragma unroll
    for (int j = 0; j < 8; ++j) o[j] = (short)f2bf(acc[j]);
    *reinterpret_cast<bf16x8*>(xbf + (size_t)r * D + c) = o;
}

// ================================================================ MFMA GEMM v3: A direct global->reg, W-only LDS,
// LDS-transpose epilogue (reuses W tile): 8x fewer, fully-coalesced stores.
// MODE 1: A=relu(bn(in)); MODE 2: A=in. In-place safe: all A-loads are
// consumed (vmcnt-drained) by every wave before the store-phase barrier.
constexpr int CSTRIDE = D + 8;   // u16 stride for the C transpose buffer (bank-spread)

template <int MODE>
__global__ __launch_bounds__(256) void gemm_mfma(
    const u16* __restrict__ A, const u16* __restrict__ Wt, const float* __restrict__ bias,
    const float* __restrict__ pSum, const float* __restrict__ pSq,
    const float* __restrict__ bng, const float* __restrict__ bnb, float invN,
    u16* __restrict__ outP, float* __restrict__ gsum, float* __restrict__ gsq,
    int nRows) {
    __shared__ u16 wLx[D * CSTRIDE];   // 34 KB: W (swizzled, first 32KB) then reused as C-transpose
    __shared__ float redS[D], redQ[D];
    __shared__ float scL[D], shL[D];

    const int tid = threadIdx.x;
    const int row0 = blockIdx.x * 128;
    const int lane = tid & 63;
    const int wv = tid >> 6;
    const int wrow = wv * 32;
    const int lr = lane & 15;
    const int lb = lane >> 4;

    // --- issue A-fragment loads early (raw bf16, latency hidden by W staging)
    bf16x8 aR[2][4];
    bool valid[2];
#pragma unroll
    for (int m = 0; m < 2; ++m) {
        int row = row0 + wrow + m * 16 + lr;
        valid[m] = row < nRows;
        const u16* p = A + (size_t)(valid[m] ? row : (nRows - 1)) * D + lb * 8;
#pragma unroll
        for (int kk = 0; kk < 4; ++kk)
            aR[m][kk] = *reinterpret_cast<const bf16x8*>(p + kk * 32);
    }

    // --- stage W (32 KB, swizzled)
    for (int o = tid * 8; o < D * D; o += 2048) {
        bf16x8 v = *reinterpret_cast<const bf16x8*>(Wt + o);
        int byte = o * 2, r = byte >> 8;
        *reinterpret_cast<bf16x8*>((char*)wLx + (byte ^ ((r & 7) << 4))) = v;
    }
    if (tid < D) {
        redS[tid] = 0.f; redQ[tid] = 0.f;
        if (MODE == 1) {
            float m = pSum[tid] * invN;
            float v = pSq[tid] * invN - m * m;
            float sc = bng[tid] * rsqrtf(v + BN_EPS);
            scL[tid] = sc;
            shL[tid] = bnb[tid] - m * sc;
        }
    }
    __syncthreads();

    // --- MODE1: BN+ReLU transform in registers
    if (MODE == 1) {
#pragma unroll
        for (int m = 0; m < 2; ++m)
#pragma unroll
            for (int kk = 0; kk < 4; ++kk)
#pragma unroll
                for (int j = 0; j < 8; ++j) {
                    int c = kk * 32 + lb * 8 + j;
                    float t = fmaxf(bf2f((u16)aR[m][kk][j]) * scL[c] + shL[c], 0.f);
                    aR[m][kk][j] = (short)f2bf(t);
                }
    }
#pragma unroll
    for (int m = 0; m < 2; ++m)
        if (!valid[m])
#pragma unroll
            for (int kk = 0; kk < 4; ++kk) aR[m][kk] = bf16x8{};

    // --- MFMA: 64 x 16x16x32
    f32x4 acc[2][8] = {};
#pragma unroll
    for (int kk = 0; kk < 4; ++kk) {
#pragma unroll
        for (int n = 0; n < 8; ++n) {
            int cr = n * 16 + lr;
            int byte = cr * 256 + kk * 64 + lb * 16;
            bf16x8 bF = *reinterpret_cast<const bf16x8*>((char*)wLx + (byte ^ ((cr & 7) << 4)));
            acc[0][n] = __builtin_amdgcn_mfma_f32_16x16x32_bf16(aR[0][kk], bF, acc[0][n], 0, 0, 0);
            acc[1][n] = __builtin_amdgcn_mfma_f32_16x16x32_bf16(aR[1][kk], bF, acc[1][n], 0, 0, 0);
        }
    }
    __syncthreads();   // all waves done reading W -> wLx reusable as C-transpose

    // --- epilogue pt1: bias + stats (guarded, f32 pre-round) + bf16 into LDS transpose
    float ls[8], lq[8];
#pragma unroll
    for (int n = 0; n < 8; ++n) { ls[n] = 0.f; lq[n] = 0.f; }
#pragma unroll
    for (int n = 0; n < 8; ++n) {
        int col = n * 16 + lr;
        float bv = bias[col];
#pragma unroll
        for (int m = 0; m < 2; ++m) {
#pragma unroll
            for (int j = 0; j < 4; ++j) {
                int rloc = wrow + m * 16 + lb * 4 + j;
                float o = acc[m][n][j] + bv;
                wLx[rloc * CSTRIDE + col] = f2bf(o);
                if (row0 + rloc < nRows) { ls[n] += o; lq[n] += o * o; }
            }
        }
    }
#pragma unroll
    for (int n = 0; n < 8; ++n) {
        float s = ls[n], q = lq[n];
        s += __shfl_xor(s, 16); q += __shfl_xor(q, 16);
        s += __shfl_xor(s, 32); q += __shfl_xor(q, 32);
        if (lb == 0) {
            atomicAdd(&redS[n * 16 + lr], s);
            atomicAdd(&redQ[n * 16 + lr], q);
        }
    }
    __syncthreads();

    // --- epilogue pt2: coalesced stores (thread -> half row, 8 x 16B)
    {
        int rloc = tid >> 1;
        int row = row0 + rloc;
        if (row < nRows) {
            const int c0 = (tid & 1) * 64;
            const u16* srcL = wLx + rloc * CSTRIDE + c0;
            u16* dstG = outP + (size_t)row * D + c0;
#pragma unroll
            for (int q = 0; q < 8; ++q)
                *reinterpret_cast<bf16x8*>(dstG + q * 8) =
                    *reinterpret_cast<const bf16x8*>(srcL + q * 8);
        }
    }
    if (tid < D) {
        atomicAdd(&gsum[tid], redS[tid]);
        atomicAdd(&gsq[tid], redQ[tid]);
    }
}

// ================================================================ stats of relu(bn2(z)), z in bf16
__global__ __launch_bounds__(256) void relu_bn_stats(const u16* __restrict__ z,
                                                     const float* __restrict__ pSum, const float* __restrict__ pSq,
                                                     const float* __restrict__ bng, const float* __restrict__ bnb,
                                                     float invN,
                                                     float* __restrict__ gsum, float* __restrict__ gsq,
                                                     long long n8) {
    __shared__ float redS[D], redQ[D];
    const int tid = threadIdx.x;
    if (tid < D) { redS[tid] = 0.f; redQ[tid] = 0.f; }
    __syncthreads();
    const int c = (tid & 15) * 8;
    float sc[8], sh[8];
#pragma unroll
    for (int j = 0; j < 8; ++j) {
        float m = pSum[c + j] * invN;
        float v = pSq[c + j] * invN - m * m;
        float s = bng[c + j] * rsqrtf(v + BN_EPS);
        sc[j] = s;
        sh[j] = bnb[c + j] - m * s;
    }
    const long long stride = (long long)gridDim.x * blockDim.x;
    float ls[8] = {}, lq[8] = {};
    for (long long i = (long long)blockIdx.x * blockDim.x + tid; i < n8; i += stride) {
        bf16x8 v = *reinterpret_cast<const bf16x8*>(z + i * 8);
#pragma unroll
        for (int j = 0; j < 8; ++j) {
            float t = fmaxf(bf2f((u16)v[j]) * sc[j] + sh[j], 0.f);
            ls[j] += t; lq[j] += t * t;
        }
    }
#pragma unroll
    for (int j = 0; j < 8; ++j) {
        atomicAdd(&redS[c + j], ls[j]);
        atomicAdd(&redQ[c + j], lq[j]);
    }
    __syncthreads();
    if (tid < D) {
        atomicAdd(&gsum[tid], redS[tid]);
        atomicAdd(&gsq[tid], redQ[tid]);
    }
}

// ================================================================ h = relu(bn3(relu(bn2(z)))) -> hbf (bf16) + pooling (fp32)
__global__ __launch_bounds__(256) void final_apply_pool(
    const u16* __restrict__ z, const int* __restrict__ gid,
    const float* __restrict__ p1S, const float* __restrict__ p1Q,
    const float* __restrict__ g2, const float* __restrict__ b2v,
    const float* __restrict__ p2S, const float* __restrict__ p2Q,
    const float* __restrict__ g3, const float* __restrict__ b3v,
    float invN, u16* __restrict__ hbf, float* __restrict__ pooled, int nRows) {
    const int tid = threadIdx.x;
    const int c = tid & 127;
    const int rsub = tid >> 7;
    const long long row0 = (long long)blockIdx.x * 64;

    float m = p1S[c] * invN;
    float va = p1Q[c] * invN - m * m;
    float a2 = g2[c] * rsqrtf(va + BN_EPS);
    float f2v = b2v[c] - m * a2;
    m = p2S[c] * invN;
    va = p2Q[c] * invN - m * m;
    float a3 = g3[c] * rsqrtf(va + BN_EPS);
    float f3v = b3v[c] - m * a3;

    float acc = 0.f;
    int cur = -1;
    for (int r = rsub; r < 64; r += 2) {
        long long row = row0 + r;
        if (row >= nRows) break;
        float v = bf2f(z[row * D + c]);
        v = fmaxf(fmaxf(v * a2 + f2v, 0.f) * a3 + f3v, 0.f);
        hbf[row * D + c] = f2bf(v);
        int g = gid[row];
        if (g != cur) {
            if (cur >= 0) atomicAdd(&pooled[(long long)cur * D + c], acc);
            cur = g;
            acc = 0.f;
        }
        acc += v;
    }
    if (cur >= 0) atomicAdd(&pooled[(long long)cur * D + c], acc);
}

// ================================================================ prediction heads: one block per graph
__global__ __launch_bounds__(256) void pred_heads(const float* __restrict__ pooled0,
                                                  const float* __restrict__ pooledL,
                                                  const float* __restrict__ pW,
                                                  const float* __restrict__ pb,
                                                  float* __restrict__ score) {
    __shared__ float red[256];
    __shared__ float pL[D];
    const int g = blockIdx.x;
    const int o = threadIdx.x & 63;
    const int ks = threadIdx.x >> 6;           // 0..3, each covers 32 k's
    float acc = 0.f;
    for (int i = 0; i <= L; ++i) {
        const float* p = (i == 0) ? (pooled0 + (size_t)g * D)
                                  : (pooledL + (size_t)(i - 1) * G * D + (size_t)g * D);
        if (threadIdx.x < D) pL[threadIdx.x] = p[threadIdx.x];
        __syncthreads();
        const float* w = pW + (size_t)i * D * OUT + (size_t)ks * 32 * OUT + o;
        float s = 0.f;
#pragma unroll
        for (int kk = 0; kk < 32; ++kk)
            s += pL[ks * 32 + kk] * w[kk * OUT];
        acc += s;
        if (ks == 0) acc += pb[i * OUT + o];
        __syncthreads();
    }
    red[threadIdx.x] = acc;
    __syncthreads();
    if (ks == 0)
        score[(size_t)g * OUT + o] = red[o] + red[64 + o] + red[128 + o] + red[192 + o];
}

// ================================================================
extern "C" void kernel_launch(void* const* d_in, const int* in_sizes, int n_in,
                              void* d_out, int out_size, void* d_ws, size_t ws_size,
                              hipStream_t stream) {
    const float* h0  = (const float*)d_in[0];
    const int*   src = (const int*)d_in[2];
    const int*   dst = (const int*)d_in[3];
    const int*   gid = (const int*)d_in[4];
    const float* eps = (const float*)d_in[5];
    const float* W1  = (const float*)d_in[6];
    const float* b1  = (const float*)d_in[7];
    const float* W2  = (const float*)d_in[8];
    const float* b2  = (const float*)d_in[9];
    const float* bn1g = (const float*)d_in[10];
    const float* bn1b = (const float*)d_in[11];
    const float* bn2g = (const float*)d_in[12];
    const float* bn2b = (const float*)d_in[13];
    const float* bn3g = (const float*)d_in[14];
    const float* bn3b = (const float*)d_in[15];
    const float* pW  = (const float*)d_in[16];
    const float* pb  = (const float*)d_in[17];

    const int N = in_sizes[0] / D;   // N < 2^17 assumed by packed-edge format
    const int E = in_sizes[2];
    const size_t nd = (size_t)N * D;
    const int numB = (N + BNODES - 1) >> BSH;

    // ---- workspace layout
    u16*   hbf  = (u16*)d_ws;                // N*D bf16
    u16*   xbf  = hbf + nd;                  // N*D bf16 (x -> y -> z in place)
    u16*   Wt   = xbf + nd;                  // 2L*D*D bf16
    float* stats = (float*)(Wt + (size_t)2 * L * D * D);  // L*3 pairs of [128+128]
    float* pooled0 = stats + (size_t)L * 3 * 2 * D;       // G*D
    int*   bktCnt = (int*)(pooled0 + (size_t)G * D);      // 4096 (zeroed with stats)
    int*   bktOff = bktCnt + 4096;           // numB+1
    int*   bktCur = bktOff + 4096;           // numB
    int*   deg    = bktCur + 4096;           // N
    int*   rowptr = deg + N;                 // N+1
    int*   esrc   = rowptr + (N + 1);        // E
    int*   bsum   = esrc + E;                // scan block sums (~N/2048)
    int*   sorted = bsum + 4096;             // E packed edges

    float* score = (float*)d_out;
    float* pooledOut = score + G * OUT;      // pooled[1..4]

    auto S = [&](int i, int j) { return stats + (size_t)(i * 3 + j) * 2 * D; };
    auto Q = [&](int i, int j) { return stats + (size_t)(i * 3 + j) * 2 * D + D; };

    const int nb = (N + SCAN_CHUNK - 1) / SCAN_CHUNK;
    const int sgrid = (E + SC_CHUNK - 1) / SC_CHUNK;
    const int hgrid = (E + 2047) / 2048;
    const int poolGrid = (N + 63) / 64;
    const int ggrid = (N + 127) / 128;
    const int agrid = (N + 15) / 16;
    const long long n8 = (long long)N * (D / 8);
    const float invN = 1.0f / (float)N;

    // one memset covers stats + pooled0 + bktCnt (contiguous)
    const size_t zeroBytes = ((size_t)L * 3 * 2 * D + (size_t)G * D) * sizeof(float) + 4096 * sizeof(int);
    hipMemsetAsync(stats, 0, zeroBytes, stream);
    hipMemsetAsync(d_out, 0, (size_t)out_size * sizeof(float), stream);

    // ---- CSR build (bucket-sorted) + weight prep
    bucket_hist<<<hgrid, 256, 0, stream>>>(dst, bktCnt, E, numB);
    prep_weights<<<2 * L, 256, 0, stream>>>(W1, W2, Wt);
    scan_buckets<<<1, 256, 0, stream>>>(bktCnt, bktOff, bktCur, numB, E);
    bucket_scatter<<<sgrid, 256, 0, stream>>>(src, dst, bktCur, sorted, E, numB);
    bucket_deg<<<numB, 256, 0, stream>>>(sorted, bktOff, deg, N);
    scan_pass1<<<nb, SCAN_B, 0, stream>>>(deg, rowptr, bsum, N);
    scan_pass2<<<1, 64, 0, stream>>>(bsum, nb);
    scan_pass3<<<nb, SCAN_B, 0, stream>>>(rowptr, bsum, N, E);
    csr_fill2<<<numB, 256, 0, stream>>>(sorted, bktOff, rowptr, esrc, N);

    // ---- h0 -> bf16 + pool0
    convert_pool<<<poolGrid, 256, 0, stream>>>(h0, gid, hbf, pooled0, N);

    for (int i = 0; i < L; ++i) {
        agg_gather<<<agrid, 256, 0, stream>>>(hbf, rowptr, esrc, eps + i, xbf, N);

        // y = x @ W1 + b1 (bf16, in place on xbf) + stats P0
        gemm_mfma<2><<<ggrid, 256, 0, stream>>>(
            xbf, Wt + (size_t)i * D * D, b1 + (size_t)i * D,
            nullptr, nullptr, nullptr, nullptr, invN,
            xbf, S(i, 0), Q(i, 0), N);

        // z = relu(bn1(y)) @ W2 + b2 (bf16, in place on xbf) + stats P1
        gemm_mfma<1><<<ggrid, 256, 0, stream>>>(
            xbf, Wt + (size_t)(L + i) * D * D, b2 + (size_t)i * D,
            S(i, 0), Q(i, 0), bn1g + (size_t)i * D, bn1b + (size_t)i * D, invN,
            xbf, S(i, 1), Q(i, 1), N);

        // stats P2 of relu(bn2(z))
        relu_bn_stats<<<1024, 256, 0, stream>>>(
            xbf, S(i, 1), Q(i, 1), bn2g + (size_t)i * D, bn2b + (size_t)i * D, invN,
            S(i, 2), Q(i, 2), n8);

        // h = relu(bn3(relu(bn2(z)))) -> hbf + pooled
        final_apply_pool<<<poolGrid, 256, 0, stream>>>(
            xbf, gid,
            S(i, 1), Q(i, 1), bn2g + (size_t)i * D, bn2b + (size_t)i * D,
            S(i, 2), Q(i, 2), bn3g + (size_t)i * D, bn3b + (size_t)i * D,
            invN, hbf, pooledOut + (size_t)i * G * D, N);
    }

    pred_heads<<<G, 256, 0, stream>>>(pooled0, pooledOut, pW, pb, score);
}